// Round 3
// baseline (677.769 us; speedup 1.0000x reference)
//
#include <hip/hip_runtime.h>
#include <math.h>

typedef __attribute__((ext_vector_type(8))) short short8;
typedef __attribute__((ext_vector_type(4))) float floatx4;

// fp32 -> bf16, round-to-nearest-even, bit pattern in a short
__device__ __forceinline__ short f2bf(float f) {
  union { float f; unsigned u; } v; v.f = f;
  unsigned r = v.u + 0x7fffu + ((v.u >> 16) & 1u);
  return (short)(r >> 16);
}

struct Params {
  const float* fs[5];
  const float* ft[5];
  const float* bias[5];
  const float* mask[5];
  const short8* wp[5];
  float* sums;
};

// ---------------------------------------------------------------------------
// Fused prep kernel: blocks 0..159 prepack adapt_w into bf16 MFMA A-fragment
// order; blocks 160..199 rasterize gt-box masks; block 200 zeroes sums.
// ---------------------------------------------------------------------------
__global__ void prep(const float* __restrict__ w0, const float* __restrict__ w1,
                     const float* __restrict__ w2, const float* __restrict__ w3,
                     const float* __restrict__ w4, short8* __restrict__ wp,
                     const float* __restrict__ gtb, float* __restrict__ mask_base,
                     float* __restrict__ sums) {
  __shared__ int lx[16], ly[16], rx[16], ry[16], dg[16];
  int blk = blockIdx.x;
  if (blk < 160) {
    int id = blk * 256 + threadIdx.x;        // exactly 5*8192 ids
    int lvl = id >> 13;
    int idx = id & 8191;
    const float* W = (lvl == 0) ? w0 : (lvl == 1) ? w1 : (lvl == 2) ? w2 : (lvl == 3) ? w3 : w4;
    int t16 = idx >> 9;
    int kt  = (idx >> 6) & 7;
    int ln  = idx & 63;
    int m = t16 * 16 + (ln & 15);
    int c = kt * 32 + (ln >> 4) * 8;
    const float* s = W + m * 256 + c;
    short8 v;
#pragma unroll
    for (int j = 0; j < 8; j++) v[j] = f2bf(s[j]);
    wp[id] = v;
  } else if (blk < 200) {
    const int szs[5]  = {128, 64, 32, 16, 8};
    const int strd[5] = {8, 16, 32, 64, 128};
    const int offs[5] = {0, 131072, 163840, 172032, 174080};
    int idx = blk - 160;
    int b = idx & 7, lvl = idx >> 3;
    int hw = szs[lvl];
    int P = hw * hw;
    if (threadIdx.x < 16) {
      int n = threadIdx.x;
      const float* bb = gtb + (b * 16 + n) * 4;
      float inv = 1.0f / (float)strd[lvl];   // pow2 stride -> exact
      int qx1 = (int)floorf(bb[0] * inv);
      int qy1 = (int)floorf(bb[1] * inv);
      int qx2 = (int)floorf(bb[2] * inv);
      int qy2 = (int)floorf(bb[3] * inv);
      int wl = hw - 1;
      int a = min(qx1, wl), c = min(qy1, wl), d = min(qx2, wl), e = min(qy2, wl);
      lx[n] = a; ly[n] = c; rx[n] = d; ry[n] = e;
      dg[n] = (a == d) || (c == e);
    }
    __syncthreads();
    float* mp = mask_base + offs[lvl] + b * P;
    for (int p = threadIdx.x; p < P; p += blockDim.x) {
      int y = p / hw, x = p - y * hw;
      bool any = false;
#pragma unroll
      for (int n = 0; n < 16; n++) {
        bool cov = dg[n] ? (y == ly[n] && x == lx[n])
                         : (y >= ly[n] && y < ry[n] && x >= lx[n] && x < rx[n]);
        any = any || cov;
      }
      mp[p] = any ? 1.0f : 0.0f;
    }
  } else {
    if (threadIdx.x < 16) sums[threadIdx.x] = 0.f;
  }
}

// ---------------------------------------------------------------------------
// Streaming GEMM + masked loss. 1024 threads = 16 waves; block tile
// 256(o) x 256(p-strip).  All global reads are CONTIGUOUS 1KB row streams
// (fix for DRAM row/channel thrash of 256B-extent strided gathers):
//  * fs: per K-step (32 c-rows), each wave streams 2 rows (4x64-dword
//    rounds), writes f32 into padded LDS tbuf[p][34] (transpose). Frags are
//    built with ds_read_b64 + f2bf (2-way read / 4-way write conflicts).
//  * K-loop: 2-deep global prefetch, raw s_barrier + lgkmcnt(0) only
//    (in-flight global loads are never drained at a barrier).
//  * epilogue: 8 o-chunks of 32 rows; owning waves push acc through LDS
//    cbuf[p][34]; then ALL waves stream ft rows contiguously (1KB extents)
//    and accumulate the masked loss.
// Wave tiling: wave w -> o-quarter (w>>2)*64, p-quarter (w&3)*(PSTRIP/4).
// ---------------------------------------------------------------------------
template<int PL2, int SL2, int LVL>
__device__ __forceinline__ void level_body(const Params& pr, int rem, float* smem) {
  constexpr int P = 64 << PL2;
  constexpr int PSTRIP = 64 << SL2;       // 256 (64 for L4)
  constexpr int NI = PSTRIP / 64;         // MFMA n-tiles per wave
  constexpr int ROUNDS = PSTRIP / 64;     // 64-dword rounds per row stream
  constexpr int STRIPS = P / PSTRIP;

  const int tid  = threadIdx.x;
  const int lane = tid & 63;
  const int w    = tid >> 6;              // wave 0..15
  const int quad = lane >> 4, l15 = lane & 15;
  const int wq   = w >> 2;                // o-quarter
  const int p_off = (w & 3) * (PSTRIP / 4);

  const int bz = rem / STRIPS;
  const int p0 = (rem % STRIPS) * PSTRIP;

  float* tb0  = smem;                     // K-loop transpose buffers
  float* tb1  = smem + 8704;
  float* mbuf = smem + 17408;             // mask strip (<=256 f32)
  float* red  = smem + 17664;             // 32 f32 reduction slots
  float* cbuf = smem;                     // epilogue acc buffer (reuses tb0)

  const float* fsb   = pr.fs[LVL] + (size_t)bz * 256 * P + p0 + lane;
  const float* ftbp  = pr.ft[LVL] + (size_t)bz * 256 * P + p0 + lane;
  const float* maskb = pr.mask[LVL] + (size_t)bz * P + p0;
  const float* biasp = pr.bias[LVL];
  const short8* wpb  = pr.wp[LVL] + wq * 2048 + lane;   // wq*4*8*64

  if (tid < PSTRIP) mbuf[tid] = maskb[tid];

  const int c0 = 2 * w;                   // this wave's row pair per kt-chunk

  float sv[2][2][ROUNDS];                 // [kt parity][h][round]
  // ---- prologue: load kt0 + kt1, stage kt0 into tb0 ----
#pragma unroll
  for (int h = 0; h < 2; ++h) {
    const float* rp = fsb + (size_t)(c0 + h) * P;
#pragma unroll
    for (int r = 0; r < ROUNDS; ++r) sv[0][h][r] = rp[r * 64];
  }
#pragma unroll
  for (int h = 0; h < 2; ++h) {
    const float* rp = fsb + (size_t)(32 + c0 + h) * P;
#pragma unroll
    for (int r = 0; r < ROUNDS; ++r) sv[1][h][r] = rp[r * 64];
  }
#pragma unroll
  for (int h = 0; h < 2; ++h)
#pragma unroll
    for (int r = 0; r < ROUNDS; ++r)
      tb0[(r * 64 + lane) * 34 + c0 + h] = sv[0][h][r];
  asm volatile("s_waitcnt lgkmcnt(0)" ::: "memory");
  __builtin_amdgcn_s_barrier();
  asm volatile("" ::: "memory");

  floatx4 acc[4][NI];
#pragma unroll
  for (int i = 0; i < 4; ++i)
#pragma unroll
    for (int j = 0; j < NI; ++j) acc[i][j] = (floatx4){0.f, 0.f, 0.f, 0.f};

  // ---- K loop: 8 steps of K=32 ----
#pragma unroll
  for (int kt = 0; kt < 8; ++kt) {
    const int cur = kt & 1, nxt = cur ^ 1;
    if (kt < 6) {                          // prefetch rows for kt+2
#pragma unroll
      for (int h = 0; h < 2; ++h) {
        const float* rp = fsb + (size_t)((kt + 2) * 32 + c0 + h) * P;
#pragma unroll
        for (int r = 0; r < ROUNDS; ++r) sv[cur][h][r] = rp[r * 64];
      }
    }
    short8 af[4];
#pragma unroll
    for (int mi = 0; mi < 4; ++mi) af[mi] = wpb[(mi * 8 + kt) * 64];

    const float* tbc = cur ? tb1 : tb0;
    short8 bf[NI];
#pragma unroll
    for (int ni = 0; ni < NI; ++ni) {
      int pl = p_off + ni * 16 + l15;
      const float2* q2 = (const float2*)(tbc + pl * 34 + quad * 8);
      short8 v;
#pragma unroll
      for (int g = 0; g < 4; ++g) {
        float2 x = q2[g];
        v[2 * g]     = f2bf(x.x);
        v[2 * g + 1] = f2bf(x.y);
      }
      bf[ni] = v;
    }
#pragma unroll
    for (int mi = 0; mi < 4; ++mi)
#pragma unroll
      for (int ni = 0; ni < NI; ++ni)
        acc[mi][ni] = __builtin_amdgcn_mfma_f32_16x16x32_bf16(af[mi], bf[ni], acc[mi][ni], 0, 0, 0);

    if (kt < 7) {                          // stage kt+1 into the other buffer
      float* tbn = nxt ? tb1 : tb0;
#pragma unroll
      for (int h = 0; h < 2; ++h)
#pragma unroll
        for (int r = 0; r < ROUNDS; ++r)
          tbn[(r * 64 + lane) * 34 + c0 + h] = sv[nxt][h][r];
      asm volatile("s_waitcnt lgkmcnt(0)" ::: "memory");
      __builtin_amdgcn_s_barrier();
      asm volatile("" ::: "memory");
    }
  }

  // ---- epilogue: 8 o-chunks of 32 rows, ft streamed contiguously ----
  float sgt = 0.f, sbg = 0.f;
#pragma unroll
  for (int oc = 0; oc < 8; ++oc) {
    asm volatile("s_waitcnt lgkmcnt(0)" ::: "memory");
    __builtin_amdgcn_s_barrier();          // cbuf free (prev chunk read done)
    asm volatile("" ::: "memory");
    if (wq == (oc >> 1)) {                 // owning waves push acc -> cbuf
      const int mb = 2 * (oc & 1);
#pragma unroll
      for (int m2 = 0; m2 < 2; ++m2)
#pragma unroll
        for (int ni = 0; ni < NI; ++ni) {
          int pl = p_off + ni * 16 + l15;
          float* cp = cbuf + pl * 34 + m2 * 16 + quad * 4;
          floatx4 a = acc[mb + m2][ni];
          ((float2*)cp)[0] = make_float2(a[0], a[1]);
          ((float2*)(cp + 2))[0] = make_float2(a[2], a[3]);
        }
    }
    float ftv[2][ROUNDS];                  // contiguous ft row streams
#pragma unroll
    for (int h = 0; h < 2; ++h) {
      const float* rp = ftbp + (size_t)(oc * 32 + c0 + h) * P;
#pragma unroll
      for (int r = 0; r < ROUNDS; ++r) ftv[h][r] = rp[r * 64];
    }
    asm volatile("s_waitcnt lgkmcnt(0)" ::: "memory");
    __builtin_amdgcn_s_barrier();          // ft loads stay in flight
    asm volatile("" ::: "memory");
#pragma unroll
    for (int h = 0; h < 2; ++h) {
      float bv = biasp[oc * 32 + c0 + h];
#pragma unroll
      for (int r = 0; r < ROUNDS; ++r) {
        int pl = r * 64 + lane;
        float m = mbuf[pl];
        float a = cbuf[pl * 34 + (c0 + h)] + bv;
        float d = ftv[h][r] - a;
        float sq = d * d;
        sgt += sq * m;
        sbg += sq - sq * m;
      }
    }
  }

#pragma unroll
  for (int off = 32; off > 0; off >>= 1) {
    sgt += __shfl_down(sgt, off);
    sbg += __shfl_down(sbg, off);
  }
  if (lane == 0) { red[w * 2] = sgt; red[w * 2 + 1] = sbg; }
  __syncthreads();
  if (tid == 0) {
    float a = 0.f, b = 0.f;
#pragma unroll
    for (int i = 0; i < 16; ++i) { a += red[2 * i]; b += red[2 * i + 1]; }
    atomicAdd(&pr.sums[LVL * 2 + 0], a);
    atomicAdd(&pr.sums[LVL * 2 + 1], b);
  }
}

// block ranges (p-strips of 256; L4 uses 64): L0 [0,512) L1 [512,640)
// L2 [640,672) L3 [672,680) L4 [680,688)
__global__ __launch_bounds__(1024, 4) void gemm_loss_all(Params pr) {
  __shared__ float smem[17696];   // 2x8704 tbuf + 256 mask + 32 red = 70784 B
  int id = blockIdx.x;
  if (id < 512)      level_body<8, 2, 0>(pr, id,       smem);
  else if (id < 640) level_body<6, 2, 1>(pr, id - 512, smem);
  else if (id < 672) level_body<4, 2, 2>(pr, id - 640, smem);
  else if (id < 680) level_body<2, 2, 3>(pr, id - 672, smem);
  else               level_body<0, 0, 4>(pr, id - 680, smem);
}

__global__ void finalize(const float* __restrict__ sums, float* __restrict__ out) {
  if (threadIdx.x == 0 && blockIdx.x == 0) {
    float L = 0.f;
#pragma unroll
    for (int i = 0; i < 5; i++)
      L += 0.004f * sqrtf(sums[2 * i] + 1e-8f) + 0.0002f * sqrtf(sums[2 * i + 1] + 1e-8f);
    out[0] = L;
  }
}

extern "C" void kernel_launch(void* const* d_in, const int* in_sizes, int n_in,
                              void* d_out, int out_size, void* d_ws, size_t ws_size,
                              hipStream_t stream) {
  (void)in_sizes; (void)n_in; (void)out_size; (void)ws_size;
  const float* fs[5]; const float* ftp[5]; const float* aw[5]; const float* ab[5];
  for (int i = 0; i < 5; i++) {
    fs[i]  = (const float*)d_in[4 * i + 0];
    ftp[i] = (const float*)d_in[4 * i + 1];
    aw[i]  = (const float*)d_in[4 * i + 2];
    ab[i]  = (const float*)d_in[4 * i + 3];
  }
  const float* gtb = (const float*)d_in[20];
  float* out = (float*)d_out;
  char* ws = (char*)d_ws;

  float*  sums  = (float*)ws;                    // 16 floats (10 used)
  float*  masks = (float*)(ws + 64);             // 174592 floats
  short8* wp    = (short8*)(ws + 64 + 698368);   // 5 * 8192 short8, 16B aligned

  prep<<<201, 256, 0, stream>>>(aw[0], aw[1], aw[2], aw[3], aw[4], wp, gtb, masks, sums);

  const int moff[5] = {0, 131072, 163840, 172032, 174080};
  Params pr;
  for (int l = 0; l < 5; l++) {
    pr.fs[l]   = fs[l];
    pr.ft[l]   = ftp[l];
    pr.bias[l] = ab[l];
    pr.mask[l] = masks + moff[l];
    pr.wp[l]   = wp + l * 8192;
  }
  pr.sums = sums;

  gemm_loss_all<<<688, 1024, 0, stream>>>(pr);
  finalize<<<1, 64, 0, stream>>>(sums, out);
}

// Round 4
// 440.905 us; speedup vs baseline: 1.5372x; 1.5372x over previous
//
#include <hip/hip_runtime.h>
#include <math.h>

typedef __attribute__((ext_vector_type(8))) short short8;
typedef __attribute__((ext_vector_type(4))) float floatx4;

// fp32 -> bf16, round-to-nearest-even, bit pattern in a short
__device__ __forceinline__ short f2bf(float f) {
  union { float f; unsigned u; } v; v.f = f;
  unsigned r = v.u + 0x7fffu + ((v.u >> 16) & 1u);
  return (short)(r >> 16);
}

struct Params {
  const float* fs[5];
  const float* ft[5];
  const float* bias[5];
  const float* mask[5];
  const short8* wp[5];
  float* sums;
};

// ---------------------------------------------------------------------------
// Fused prep kernel: blocks 0..159 prepack adapt_w into bf16 MFMA A-fragment
// order; blocks 160..199 rasterize gt-box masks; block 200 zeroes sums.
// ---------------------------------------------------------------------------
__global__ void prep(const float* __restrict__ w0, const float* __restrict__ w1,
                     const float* __restrict__ w2, const float* __restrict__ w3,
                     const float* __restrict__ w4, short8* __restrict__ wp,
                     const float* __restrict__ gtb, float* __restrict__ mask_base,
                     float* __restrict__ sums) {
  __shared__ int lx[16], ly[16], rx[16], ry[16], dg[16];
  int blk = blockIdx.x;
  if (blk < 160) {
    int id = blk * 256 + threadIdx.x;        // exactly 5*8192 ids
    int lvl = id >> 13;
    int idx = id & 8191;
    const float* W = (lvl == 0) ? w0 : (lvl == 1) ? w1 : (lvl == 2) ? w2 : (lvl == 3) ? w3 : w4;
    int t16 = idx >> 9;
    int kt  = (idx >> 6) & 7;
    int ln  = idx & 63;
    int m = t16 * 16 + (ln & 15);
    int c = kt * 32 + (ln >> 4) * 8;
    const float* s = W + m * 256 + c;
    short8 v;
#pragma unroll
    for (int j = 0; j < 8; j++) v[j] = f2bf(s[j]);
    wp[id] = v;
  } else if (blk < 200) {
    const int szs[5]  = {128, 64, 32, 16, 8};
    const int strd[5] = {8, 16, 32, 64, 128};
    const int offs[5] = {0, 131072, 163840, 172032, 174080};
    int idx = blk - 160;
    int b = idx & 7, lvl = idx >> 3;
    int hw = szs[lvl];
    int P = hw * hw;
    if (threadIdx.x < 16) {
      int n = threadIdx.x;
      const float* bb = gtb + (b * 16 + n) * 4;
      float inv = 1.0f / (float)strd[lvl];   // pow2 stride -> exact
      int qx1 = (int)floorf(bb[0] * inv);
      int qy1 = (int)floorf(bb[1] * inv);
      int qx2 = (int)floorf(bb[2] * inv);
      int qy2 = (int)floorf(bb[3] * inv);
      int wl = hw - 1;
      int a = min(qx1, wl), c = min(qy1, wl), d = min(qx2, wl), e = min(qy2, wl);
      lx[n] = a; ly[n] = c; rx[n] = d; ry[n] = e;
      dg[n] = (a == d) || (c == e);
    }
    __syncthreads();
    float* mp = mask_base + offs[lvl] + b * P;
    for (int p = threadIdx.x; p < P; p += blockDim.x) {
      int y = p / hw, x = p - y * hw;
      bool any = false;
#pragma unroll
      for (int n = 0; n < 16; n++) {
        bool cov = dg[n] ? (y == ly[n] && x == lx[n])
                         : (y >= ly[n] && y < ry[n] && x >= lx[n] && x < rx[n]);
        any = any || cov;
      }
      mp[p] = any ? 1.0f : 0.0f;
    }
  } else {
    if (threadIdx.x < 16) sums[threadIdx.x] = 0.f;
  }
}

// ---------------------------------------------------------------------------
// Streaming GEMM + masked loss. 512 threads = 8 waves; block tile
// 256(o) x 128(p-strip).  All global reads are CONTIGUOUS row streams:
//  * fs: per K-step (32 c-rows), each wave streams 4 rows (ROUNDS x 64
//    dwords each), writes f32 into padded LDS tbuf[p][34] (transpose).
//    Frags built with 2-dword LDS reads + f2bf.
//  * K-loop: 2-deep global prefetch, raw s_barrier + lgkmcnt(0) only
//    (in-flight global loads are never drained at a barrier).
//  * epilogue: 8 o-chunks of 32 rows; owning waves push acc through LDS
//    cbuf[p][34]; all waves stream ft rows contiguously.
// Register budget (the round-3 lesson): 8-wave blocks with
// __launch_bounds__(512,2) -> 256-VGPR cap; ~145 VGPRs needed -> NO SPILLS.
// Wave tiling: wave w -> o-quarter (w>>1)*64, p-half (w&1)*(PSTRIP/2).
// ---------------------------------------------------------------------------
template<int PL2, int SL2, int LVL>
__device__ __forceinline__ void level_body(const Params& pr, int rem, float* smem) {
  constexpr int P = 64 << PL2;            // pixels per image at this level
  constexpr int PSTRIP = 64 << SL2;       // 128 (64 for L4)
  constexpr int NI = PSTRIP / 32;         // 16p MFMA tiles per wave (half strip)
  constexpr int ROUNDS = PSTRIP / 64;     // 64-dword rounds per row stream
  constexpr int STRIPS = P / PSTRIP;

  const int tid  = threadIdx.x;
  const int lane = tid & 63;
  const int w    = tid >> 6;              // wave 0..7
  const int quad = lane >> 4, l15 = lane & 15;
  const int wq   = w >> 1;                // o-quarter
  const int p_off = (w & 1) * (PSTRIP / 2);

  const int bz = rem / STRIPS;
  const int p0 = (rem % STRIPS) * PSTRIP;

  float* tb0  = smem;                     // K-loop transpose buffers
  float* tb1  = smem + PSTRIP * 34;
  float* mbuf = smem + 2 * PSTRIP * 34;   // mask strip
  float* red  = mbuf + PSTRIP;            // 16 f32 reduction slots
  float* cbuf = smem;                     // epilogue acc buffer (reuses tb0)

  const float* fsb   = pr.fs[LVL] + (size_t)bz * 256 * P + p0 + lane;
  const float* ftbp  = pr.ft[LVL] + (size_t)bz * 256 * P + p0 + lane;
  const float* maskb = pr.mask[LVL] + (size_t)bz * P + p0;
  const float* biasp = pr.bias[LVL];
  const short8* wpb  = pr.wp[LVL] + wq * 2048 + lane;   // t16 = wq*4 + mi

  if (tid < PSTRIP) mbuf[tid] = maskb[tid];

  const int c0 = 4 * w;                   // this wave's 4 rows per kt-chunk

  float sv[2][4][ROUNDS];                 // [kt parity][row][round]
  // ---- prologue: load kt0 + kt1, stage kt0 into tb0 ----
#pragma unroll
  for (int h = 0; h < 4; ++h) {
    const float* rp = fsb + (size_t)(c0 + h) * P;
#pragma unroll
    for (int r = 0; r < ROUNDS; ++r) sv[0][h][r] = rp[r * 64];
  }
#pragma unroll
  for (int h = 0; h < 4; ++h) {
    const float* rp = fsb + (size_t)(32 + c0 + h) * P;
#pragma unroll
    for (int r = 0; r < ROUNDS; ++r) sv[1][h][r] = rp[r * 64];
  }
#pragma unroll
  for (int h = 0; h < 4; ++h)
#pragma unroll
    for (int r = 0; r < ROUNDS; ++r)
      tb0[(r * 64 + lane) * 34 + c0 + h] = sv[0][h][r];
  asm volatile("s_waitcnt lgkmcnt(0)" ::: "memory");
  __builtin_amdgcn_s_barrier();
  asm volatile("" ::: "memory");

  floatx4 acc[4][NI];
#pragma unroll
  for (int i = 0; i < 4; ++i)
#pragma unroll
    for (int j = 0; j < NI; ++j) acc[i][j] = (floatx4){0.f, 0.f, 0.f, 0.f};

  // ---- K loop: 8 steps of K=32, fully unrolled ----
#pragma unroll
  for (int kt = 0; kt < 8; ++kt) {
    const int cur = kt & 1, nxt = cur ^ 1;
    if (kt < 6) {                          // prefetch rows for kt+2
#pragma unroll
      for (int h = 0; h < 4; ++h) {
        const float* rp = fsb + (size_t)((kt + 2) * 32 + c0 + h) * P;
#pragma unroll
        for (int r = 0; r < ROUNDS; ++r) sv[cur][h][r] = rp[r * 64];
      }
    }
    short8 af[4];
#pragma unroll
    for (int mi = 0; mi < 4; ++mi) af[mi] = wpb[(mi * 8 + kt) * 64];

    const float* tbc = cur ? tb1 : tb0;
    short8 bf[NI];
#pragma unroll
    for (int ni = 0; ni < NI; ++ni) {
      int pl = p_off + ni * 16 + l15;
      const float2* q2 = (const float2*)(tbc + pl * 34 + quad * 8);
      short8 v;
#pragma unroll
      for (int g = 0; g < 4; ++g) {
        float2 x = q2[g];
        v[2 * g]     = f2bf(x.x);
        v[2 * g + 1] = f2bf(x.y);
      }
      bf[ni] = v;
    }
#pragma unroll
    for (int mi = 0; mi < 4; ++mi)
#pragma unroll
      for (int ni = 0; ni < NI; ++ni)
        acc[mi][ni] = __builtin_amdgcn_mfma_f32_16x16x32_bf16(af[mi], bf[ni], acc[mi][ni], 0, 0, 0);

    if (kt < 7) {                          // stage kt+1 into the other buffer
      float* tbn = nxt ? tb1 : tb0;
#pragma unroll
      for (int h = 0; h < 4; ++h)
#pragma unroll
        for (int r = 0; r < ROUNDS; ++r)
          tbn[(r * 64 + lane) * 34 + c0 + h] = sv[nxt][h][r];
      asm volatile("s_waitcnt lgkmcnt(0)" ::: "memory");
      __builtin_amdgcn_s_barrier();
      asm volatile("" ::: "memory");
    }
  }

  // ---- epilogue: 8 o-chunks of 32 rows, ft streamed contiguously ----
  float sgt = 0.f, sbg = 0.f;
#pragma unroll
  for (int oc = 0; oc < 8; ++oc) {
    asm volatile("s_waitcnt lgkmcnt(0)" ::: "memory");
    __builtin_amdgcn_s_barrier();          // cbuf free (prev chunk reads done)
    asm volatile("" ::: "memory");
    if (wq == (oc >> 1)) {                 // owning waves push acc -> cbuf
      const int mb = 2 * (oc & 1);
#pragma unroll
      for (int m2 = 0; m2 < 2; ++m2)
#pragma unroll
        for (int ni = 0; ni < NI; ++ni) {
          int pl = p_off + ni * 16 + l15;
          float* cp = cbuf + pl * 34 + m2 * 16 + quad * 4;
          floatx4 a = acc[mb + m2][ni];
          ((float2*)cp)[0] = make_float2(a[0], a[1]);
          ((float2*)(cp + 2))[0] = make_float2(a[2], a[3]);
        }
    }
    float ftv[4][ROUNDS];                  // contiguous ft row streams
#pragma unroll
    for (int h = 0; h < 4; ++h) {
      const float* rp = ftbp + (size_t)(oc * 32 + c0 + h) * P;
#pragma unroll
      for (int r = 0; r < ROUNDS; ++r) ftv[h][r] = rp[r * 64];
    }
    asm volatile("s_waitcnt lgkmcnt(0)" ::: "memory");
    __builtin_amdgcn_s_barrier();          // ft loads stay in flight
    asm volatile("" ::: "memory");
#pragma unroll
    for (int h = 0; h < 4; ++h) {
      float bv = biasp[oc * 32 + c0 + h];
#pragma unroll
      for (int r = 0; r < ROUNDS; ++r) {
        int pl = r * 64 + lane;
        float m = mbuf[pl];
        float a = cbuf[pl * 34 + (c0 + h)] + bv;
        float d = ftv[h][r] - a;
        float sq = d * d;
        sgt += sq * m;
        sbg += sq - sq * m;
      }
    }
  }

#pragma unroll
  for (int off = 32; off > 0; off >>= 1) {
    sgt += __shfl_down(sgt, off);
    sbg += __shfl_down(sbg, off);
  }
  if (lane == 0) { red[w * 2] = sgt; red[w * 2 + 1] = sbg; }
  __syncthreads();
  if (tid == 0) {
    float a = 0.f, b = 0.f;
#pragma unroll
    for (int i = 0; i < 8; ++i) { a += red[2 * i]; b += red[2 * i + 1]; }
    atomicAdd(&pr.sums[LVL * 2 + 0], a);
    atomicAdd(&pr.sums[LVL * 2 + 1], b);
  }
}

// block ranges (p-strips of 128; L4 uses 64): L0 [0,1024) L1 [1024,1280)
// L2 [1280,1344) L3 [1344,1360) L4 [1360,1368)
__global__ __launch_bounds__(512, 2) void gemm_loss_all(Params pr) {
  __shared__ float smem[8848];   // 2x(128*34) tbuf + 128 mask + 16 red = 35392 B
  int id = blockIdx.x;
  if (id < 1024)      level_body<8, 1, 0>(pr, id,        smem);
  else if (id < 1280) level_body<6, 1, 1>(pr, id - 1024, smem);
  else if (id < 1344) level_body<4, 1, 2>(pr, id - 1280, smem);
  else if (id < 1360) level_body<2, 1, 3>(pr, id - 1344, smem);
  else                level_body<0, 0, 4>(pr, id - 1360, smem);
}

__global__ void finalize(const float* __restrict__ sums, float* __restrict__ out) {
  if (threadIdx.x == 0 && blockIdx.x == 0) {
    float L = 0.f;
#pragma unroll
    for (int i = 0; i < 5; i++)
      L += 0.004f * sqrtf(sums[2 * i] + 1e-8f) + 0.0002f * sqrtf(sums[2 * i + 1] + 1e-8f);
    out[0] = L;
  }
}

extern "C" void kernel_launch(void* const* d_in, const int* in_sizes, int n_in,
                              void* d_out, int out_size, void* d_ws, size_t ws_size,
                              hipStream_t stream) {
  (void)in_sizes; (void)n_in; (void)out_size; (void)ws_size;
  const float* fs[5]; const float* ftp[5]; const float* aw[5]; const float* ab[5];
  for (int i = 0; i < 5; i++) {
    fs[i]  = (const float*)d_in[4 * i + 0];
    ftp[i] = (const float*)d_in[4 * i + 1];
    aw[i]  = (const float*)d_in[4 * i + 2];
    ab[i]  = (const float*)d_in[4 * i + 3];
  }
  const float* gtb = (const float*)d_in[20];
  float* out = (float*)d_out;
  char* ws = (char*)d_ws;

  float*  sums  = (float*)ws;                    // 16 floats (10 used)
  float*  masks = (float*)(ws + 64);             // 174592 floats
  short8* wp    = (short8*)(ws + 64 + 698368);   // 5 * 8192 short8, 16B aligned

  prep<<<201, 256, 0, stream>>>(aw[0], aw[1], aw[2], aw[3], aw[4], wp, gtb, masks, sums);

  const int moff[5] = {0, 131072, 163840, 172032, 174080};
  Params pr;
  for (int l = 0; l < 5; l++) {
    pr.fs[l]   = fs[l];
    pr.ft[l]   = ftp[l];
    pr.bias[l] = ab[l];
    pr.mask[l] = masks + moff[l];
    pr.wp[l]   = wp + l * 8192;
  }
  pr.sums = sums;

  gemm_loss_all<<<1368, 512, 0, stream>>>(pr);
  finalize<<<1, 64, 0, stream>>>(sums, out);
}